// Round 3
// baseline (90.694 us; speedup 1.0000x reference)
//
#include <hip/hip_runtime.h>
#include <math.h>

#define NPART 62
#define M 512
#define D 256
#define KSAMP 8
#define MARGIN 0.2f

typedef __attribute__((ext_vector_type(8))) short bf16x8;
typedef __attribute__((ext_vector_type(4))) short s16x4;
typedef __attribute__((ext_vector_type(4))) float f32x4;

__device__ __forceinline__ unsigned bf16_rne(float f) {
    unsigned u = __builtin_bit_cast(unsigned, f);
    return (u + 0x7FFFu + ((u >> 16) & 1u)) >> 16;
}

// ---------------- prep: fp32 -> (hi,lo) bf16 planes + row norms ----------------
// Layout: hi_ws[rg*256 + kc*32 + gslot*16b..]; slot g holds k-group (g ^ sw(row)),
// sw(row) = (row ^ row>>2) & 3.  One wave per row.
__global__ __launch_bounds__(256) void triplet_prep(
    const float* __restrict__ feat, float* __restrict__ x2_ws,
    short* __restrict__ hi_ws, short* __restrict__ lo_ws)
{
    const int t  = threadIdx.x;
    const int l  = t & 63;
    const int w  = t >> 6;
    const int rg = blockIdx.x * 4 + w;          // global row (n*512+row)
    const int row = rg & (M - 1);

    const float4 v = *(const float4*)(feat + (size_t)rg * D + l * 4);
    float x2 = v.x * v.x + v.y * v.y + v.z * v.z + v.w * v.w;
    const float vf[4] = {v.x, v.y, v.z, v.w};
    s16x4 hs, ls;
#pragma unroll
    for (int e = 0; e < 4; ++e) {
        const unsigned hr = bf16_rne(vf[e]);
        hs[e] = (short)hr;
        ls[e] = (short)bf16_rne(vf[e] - __builtin_bit_cast(float, hr << 16));
    }
    const int kc = l >> 3;
    const int g  = (l >> 1) & 3;
    const int sw = (row ^ (row >> 2)) & 3;
    const size_t base = (size_t)rg * D + kc * 32 + (g ^ sw) * 8 + (l & 1) * 4;
    *(s16x4*)(hi_ws + base) = hs;
    *(s16x4*)(lo_ws + base) = ls;
#pragma unroll
    for (int o = 32; o > 0; o >>= 1) x2 += __shfl_xor(x2, o);
    if (l == 0) x2_ws[rg] = x2;
}

// ---------------- main: 4 blocks/part, 8 waves, dbuf LDS, MFMA gram ----------------
__global__ __launch_bounds__(512, 2) void triplet_main(
    const short* __restrict__ hi_ws, const short* __restrict__ lo_ws,
    const float* __restrict__ x2_ws, const int* __restrict__ label,
    float* __restrict__ ws)
{
    __shared__ short hiA[2 * M * 32];            // 64 KB (2 bufs x 32 KB)
    __shared__ short loA[2 * M * 32];            // 64 KB
    __shared__ float x2s[M];
    __shared__ int   labsS[M];
    __shared__ __align__(16) float hpL[128 * 8];
    __shared__ float hnw[128 * 4];

    const int t    = threadIdx.x;
    const int lane = t & 63;
    const int w    = t >> 6;
    const int lr   = lane & 15;
    const int h    = lane >> 4;

    // bijective XCD swizzle (248 = 8*31): part's 4 blocks land on one XCD
    const int d_ = blockIdx.x;
    const int s  = (d_ & 7) * 31 + (d_ >> 3);
    const int n  = s >> 2;
    const int bx = s & 3;
    const int R0 = bx * 128;
    const int rw = (w >> 2) * 64;
    const int cw = (w & 3) * 128;

    labsS[t] = label[n * M + t];
    x2s[t]   = x2_ws[n * M + t];

    // staging addresses: wave w copies chunks c = w*4+it (16 rows x 64B each)
    size_t gbase[4];
    int    ldst[4];
#pragma unroll
    for (int it = 0; it < 4; ++it) {
        const int c   = w * 4 + it;
        const int row = c * 16 + (lane >> 2);
        const int g   = lane & 3;
        gbase[it] = ((size_t)n * M + row) * D + g * 8;
        ldst[it]  = c * 512 + lane * 8;
    }
    // MFMA fragment LDS offsets (swizzle-corrected)
    int aOff[4], bOff[8];
#pragma unroll
    for (int rb = 0; rb < 4; ++rb) {
        const int row = R0 + rw + rb * 16 + lr;
        aOff[rb] = row * 32 + ((h ^ ((row ^ (row >> 2)) & 3)) * 8);
    }
#pragma unroll
    for (int cb = 0; cb < 8; ++cb) {
        const int row = cw + cb * 16 + lr;
        bOff[cb] = row * 32 + ((h ^ ((row ^ (row >> 2)) & 3)) * 8);
    }

    f32x4 acc[4][8];
    const f32x4 zero4 = {0.f, 0.f, 0.f, 0.f};
#pragma unroll
    for (int a = 0; a < 4; ++a)
#pragma unroll
        for (int bq = 0; bq < 8; ++bq) acc[a][bq] = zero4;

    bf16x8 sgh[4], sgl[4];
    // prologue: stage kc=0 into buf 0
#pragma unroll
    for (int it = 0; it < 4; ++it) {
        sgh[it] = *(const bf16x8*)(hi_ws + gbase[it]);
        sgl[it] = *(const bf16x8*)(lo_ws + gbase[it]);
    }
#pragma unroll
    for (int it = 0; it < 4; ++it) {
        *(bf16x8*)&hiA[ldst[it]] = sgh[it];
        *(bf16x8*)&loA[ldst[it]] = sgl[it];
    }
    __syncthreads();

    int b = 0;
    for (int kc = 0; kc < 8; ++kc) {
        if (kc < 7) {   // issue next-k loads early (hide HBM/L2 under MFMA)
            const size_t kb = (size_t)(kc + 1) * 32;
#pragma unroll
            for (int it = 0; it < 4; ++it) {
                sgh[it] = *(const bf16x8*)(hi_ws + gbase[it] + kb);
                sgl[it] = *(const bf16x8*)(lo_ws + gbase[it] + kb);
            }
        }
        const int bo = b * (M * 32);
        bf16x8 ah[4], al[4];
#pragma unroll
        for (int rb = 0; rb < 4; ++rb) {
            ah[rb] = *(const bf16x8*)&hiA[bo + aOff[rb]];
            al[rb] = *(const bf16x8*)&loA[bo + aOff[rb]];
        }
#pragma unroll
        for (int cb = 0; cb < 8; ++cb) {
            const bf16x8 bh = *(const bf16x8*)&hiA[bo + bOff[cb]];
            const bf16x8 bl = *(const bf16x8*)&loA[bo + bOff[cb]];
#pragma unroll
            for (int rb = 0; rb < 4; ++rb) {
                acc[rb][cb] = __builtin_amdgcn_mfma_f32_16x16x32_bf16(ah[rb], bh, acc[rb][cb], 0, 0, 0);
                acc[rb][cb] = __builtin_amdgcn_mfma_f32_16x16x32_bf16(al[rb], bh, acc[rb][cb], 0, 0, 0);
                acc[rb][cb] = __builtin_amdgcn_mfma_f32_16x16x32_bf16(ah[rb], bl, acc[rb][cb], 0, 0, 0);
            }
        }
        if (kc < 7) {   // write next tile into the other buffer
            const int to = (b ^ 1) * (M * 32);
#pragma unroll
            for (int it = 0; it < 4; ++it) {
                *(bf16x8*)&hiA[to + ldst[it]] = sgh[it];
                *(bf16x8*)&loA[to + ldst[it]] = sgl[it];
            }
        }
        __syncthreads();
        b ^= 1;
    }

    // ---- epilogue ----
    // acc[rb][cb][q] = G[R0 + rw + rb*16 + h*4 + q][cw + cb*16 + lr]
    float x2r[4][4]; int labr_[4][4];
#pragma unroll
    for (int rb = 0; rb < 4; ++rb)
#pragma unroll
        for (int q = 0; q < 4; ++q) {
            const int ri = R0 + rw + rb * 16 + h * 4 + q;
            x2r[rb][q]   = x2s[ri];
            labr_[rb][q] = labsS[ri];
        }
    float x2c[8]; int labc[8];
#pragma unroll
    for (int cb = 0; cb < 8; ++cb) {
        const int cj = cw + cb * 16 + lr;
        x2c[cb] = x2s[cj];
        labc[cb] = labsS[cj];
    }

    float mdsum = 0.f;
#pragma unroll
    for (int rb = 0; rb < 4; ++rb)
#pragma unroll
        for (int cb = 0; cb < 8; ++cb) {
            f32x4 a = acc[rb][cb];
#pragma unroll
            for (int q = 0; q < 4; ++q) {
                const float d2 = x2r[rb][q] + x2c[cb] - 2.f * a[q];
                const float dd = (d2 > 0.f) ? sqrtf(d2) : 0.f;
                a[q] = dd;
                mdsum += dd;
                if (labc[cb] == labr_[rb][q])
                    hpL[(rw + rb * 16 + h * 4 + q) * 8 + (lane & 7)] = dd;
            }
            acc[rb][cb] = a;
        }
    __syncthreads();

    float fsum = 0.f, fcnt = 0.f;
#pragma unroll
    for (int rb = 0; rb < 4; ++rb)
#pragma unroll
        for (int q = 0; q < 4; ++q) {
            const int rl   = rw + rb * 16 + h * 4 + q;
            const int labi = labr_[rb][q];
            const float4 hp0 = *(const float4*)&hpL[rl * 8];
            const float4 hp1 = *(const float4*)&hpL[rl * 8 + 4];
            const float mhp[8] = {MARGIN + hp0.x, MARGIN + hp0.y, MARGIN + hp0.z, MARGIN + hp0.w,
                                  MARGIN + hp1.x, MARGIN + hp1.y, MARGIN + hp1.z, MARGIN + hp1.w};
            float hn = 3.0e38f;
#pragma unroll
            for (int cb = 0; cb < 8; ++cb) {
                if (labc[cb] != labi) {
                    const float dd = acc[rb][cb][q];
                    hn = fminf(hn, dd);
#pragma unroll
                    for (int p = 0; p < 8; ++p) {
                        const float vv = mhp[p] - dd;
                        fsum += fmaxf(vv, 0.f);
                        fcnt += (vv > 0.f) ? 1.f : 0.f;
                    }
                }
            }
            hn = fminf(hn, __shfl_xor(hn, 1));
            hn = fminf(hn, __shfl_xor(hn, 2));
            hn = fminf(hn, __shfl_xor(hn, 4));
            hn = fminf(hn, __shfl_xor(hn, 8));
            if (lr == 0) hnw[rl * 4 + (w & 3)] = hn;
        }

#pragma unroll
    for (int o = 32; o > 0; o >>= 1) {
        fsum  += __shfl_xor(fsum, o);
        fcnt  += __shfl_xor(fcnt, o);
        mdsum += __shfl_xor(mdsum, o);
    }
    if (lane == 0) {
        atomicAdd(&ws[n * 4 + 0], fsum);
        atomicAdd(&ws[n * 4 + 1], fcnt);
        atomicAdd(&ws[n * 4 + 3], mdsum);
    }
    __syncthreads();

    if (t < 128) {
        const float hn = fminf(fminf(hnw[t * 4 + 0], hnw[t * 4 + 1]),
                               fminf(hnw[t * 4 + 2], hnw[t * 4 + 3]));
        float hm = hpL[t * 8];
#pragma unroll
        for (int p = 1; p < 8; ++p) hm = fmaxf(hm, hpL[t * 8 + p]);
        float hd = MARGIN + hm - hn;
        hd = (hd > 0.f) ? hd : 0.f;
#pragma unroll
        for (int o = 32; o > 0; o >>= 1) hd += __shfl_xor(hd, o);
        if (lane == 0) atomicAdd(&ws[n * 4 + 2], hd);
    }
}

// ---------------- fallback (round-2 kernel, used if ws too small) ----------------
__global__ __launch_bounds__(256, 2) void triplet_main_fb(
    const float* __restrict__ feat, const int* __restrict__ label,
    float* __restrict__ ws)
{
    __shared__ bf16x8 hiS[M * 4];
    __shared__ bf16x8 loS[M * 4];
    __shared__ float  x2s[M];
    __shared__ int    labsS[M];
    __shared__ __align__(16) float hpL[64 * 8];
    __shared__ float  hnw[64 * 4];

    const int t    = threadIdx.x;
    const int lane = t & 63;
    const int w    = t >> 6;
    const int lr   = lane & 15;
    const int h    = lane >> 4;

    const int d_ = blockIdx.x;
    const int s  = (d_ & 7) * 62 + (d_ >> 3);
    const int n  = s >> 3;
    const int bx = s & 7;
    const int R0 = bx * 64;
    const float* F = feat + (size_t)n * (M * D);

    labsS[t]       = label[n * M + t];
    labsS[t + 256] = label[n * M + t + 256];

    float x2q[8];
#pragma unroll
    for (int i = 0; i < 8; ++i) x2q[i] = 0.f;

    f32x4 acc[4][8];
    const f32x4 zero4 = {0.f, 0.f, 0.f, 0.f};
#pragma unroll
    for (int a = 0; a < 4; ++a)
#pragma unroll
        for (int bq = 0; bq < 8; ++bq) acc[a][bq] = zero4;

    int aIdx[4], bIdx[8];
#pragma unroll
    for (int rb = 0; rb < 4; ++rb) {
        const int row = R0 + rb * 16 + lr;
        aIdx[rb] = row * 4 + (h ^ ((row >> 1) & 3));
    }
#pragma unroll
    for (int cb = 0; cb < 8; ++cb) {
        const int row = w * 128 + cb * 16 + lr;
        bIdx[cb] = row * 4 + (h ^ ((row >> 1) & 3));
    }
    int sRowA[8], sDstA[8];
#pragma unroll
    for (int it = 0; it < 8; ++it) {
        const int idx = t + 256 * it;
        const int row = idx >> 2, qq = idx & 3;
        sRowA[it] = row;
        sDstA[it] = row * 4 + (qq ^ ((row >> 1) & 3));
    }
    const int qoff = (t & 3) * 8;

    for (int kc = 0; kc < 8; ++kc) {
        const int k0 = kc * 32;
        __syncthreads();
#pragma unroll
        for (int it = 0; it < 8; ++it) {
            const float* src = F + (size_t)sRowA[it] * D + k0 + qoff;
            const float4 v0 = *(const float4*)src;
            const float4 v1 = *(const float4*)(src + 4);
            const float v[8] = {v0.x, v0.y, v0.z, v0.w, v1.x, v1.y, v1.z, v1.w};
            bf16x8 h8, l8;
#pragma unroll
            for (int e = 0; e < 8; ++e) {
                const float f = v[e];
                const unsigned hr = bf16_rne(f);
                const float hf = __builtin_bit_cast(float, hr << 16);
                h8[e] = (short)hr;
                l8[e] = (short)bf16_rne(f - hf);
                x2q[it] += f * f;
            }
            hiS[sDstA[it]] = h8;
            loS[sDstA[it]] = l8;
        }
        __syncthreads();

        bf16x8 ah[4], al[4];
#pragma unroll
        for (int rb = 0; rb < 4; ++rb) { ah[rb] = hiS[aIdx[rb]]; al[rb] = loS[aIdx[rb]]; }
#pragma unroll
        for (int cb = 0; cb < 8; ++cb) {
            const bf16x8 bh = hiS[bIdx[cb]];
            const bf16x8 bl = loS[bIdx[cb]];
#pragma unroll
            for (int rb = 0; rb < 4; ++rb) {
                acc[rb][cb] = __builtin_amdgcn_mfma_f32_16x16x32_bf16(ah[rb], bh, acc[rb][cb], 0, 0, 0);
                acc[rb][cb] = __builtin_amdgcn_mfma_f32_16x16x32_bf16(al[rb], bh, acc[rb][cb], 0, 0, 0);
                acc[rb][cb] = __builtin_amdgcn_mfma_f32_16x16x32_bf16(ah[rb], bl, acc[rb][cb], 0, 0, 0);
            }
        }
    }

#pragma unroll
    for (int it = 0; it < 8; ++it) {
        float x = x2q[it];
        x += __shfl_xor(x, 1);
        x += __shfl_xor(x, 2);
        if ((t & 3) == 0) x2s[sRowA[it]] = x;
    }
    __syncthreads();

    float x2r[4][4]; int labr_[4][4];
#pragma unroll
    for (int rb = 0; rb < 4; ++rb)
#pragma unroll
        for (int q = 0; q < 4; ++q) {
            const int gi = R0 + rb * 16 + h * 4 + q;
            x2r[rb][q]   = x2s[gi];
            labr_[rb][q] = labsS[gi];
        }
    float x2c[8]; int labc[8];
#pragma unroll
    for (int cb = 0; cb < 8; ++cb) {
        const int cj = w * 128 + cb * 16 + lr;
        x2c[cb] = x2s[cj];
        labc[cb] = labsS[cj];
    }

    float mdsum = 0.f;
#pragma unroll
    for (int rb = 0; rb < 4; ++rb)
#pragma unroll
        for (int cb = 0; cb < 8; ++cb) {
            f32x4 a = acc[rb][cb];
#pragma unroll
            for (int q = 0; q < 4; ++q) {
                const float d2 = x2r[rb][q] + x2c[cb] - 2.f * a[q];
                const float dd = (d2 > 0.f) ? sqrtf(d2) : 0.f;
                a[q] = dd;
                mdsum += dd;
                if (labc[cb] == labr_[rb][q])
                    hpL[(rb * 16 + h * 4 + q) * 8 + (lane & 7)] = dd;
            }
            acc[rb][cb] = a;
        }
    __syncthreads();

    float fsum = 0.f, fcnt = 0.f;
#pragma unroll
    for (int rb = 0; rb < 4; ++rb)
#pragma unroll
        for (int q = 0; q < 4; ++q) {
            const int rl   = rb * 16 + h * 4 + q;
            const int labi = labr_[rb][q];
            const float4 hp0 = *(const float4*)&hpL[rl * 8];
            const float4 hp1 = *(const float4*)&hpL[rl * 8 + 4];
            const float mhp[8] = {MARGIN + hp0.x, MARGIN + hp0.y, MARGIN + hp0.z, MARGIN + hp0.w,
                                  MARGIN + hp1.x, MARGIN + hp1.y, MARGIN + hp1.z, MARGIN + hp1.w};
            float hn = 3.0e38f;
#pragma unroll
            for (int cb = 0; cb < 8; ++cb) {
                if (labc[cb] != labi) {
                    const float dd = acc[rb][cb][q];
                    hn = fminf(hn, dd);
#pragma unroll
                    for (int p = 0; p < 8; ++p) {
                        const float vv = mhp[p] - dd;
                        fsum += fmaxf(vv, 0.f);
                        fcnt += (vv > 0.f) ? 1.f : 0.f;
                    }
                }
            }
            hn = fminf(hn, __shfl_xor(hn, 1));
            hn = fminf(hn, __shfl_xor(hn, 2));
            hn = fminf(hn, __shfl_xor(hn, 4));
            hn = fminf(hn, __shfl_xor(hn, 8));
            if (lr == 0) hnw[rl * 4 + w] = hn;
        }

#pragma unroll
    for (int o = 32; o > 0; o >>= 1) {
        fsum  += __shfl_xor(fsum, o);
        fcnt  += __shfl_xor(fcnt, o);
        mdsum += __shfl_xor(mdsum, o);
    }
    if (lane == 0) {
        atomicAdd(&ws[n * 4 + 0], fsum);
        atomicAdd(&ws[n * 4 + 1], fcnt);
        atomicAdd(&ws[n * 4 + 3], mdsum);
    }
    __syncthreads();

    if (t < 64) {
        const float hn = fminf(fminf(hnw[t * 4 + 0], hnw[t * 4 + 1]),
                               fminf(hnw[t * 4 + 2], hnw[t * 4 + 3]));
        float hm = hpL[t * 8];
#pragma unroll
        for (int p = 1; p < 8; ++p) hm = fmaxf(hm, hpL[t * 8 + p]);
        float hd = MARGIN + hm - hn;
        hd = (hd > 0.f) ? hd : 0.f;
#pragma unroll
        for (int o = 32; o > 0; o >>= 1) hd += __shfl_xor(hd, o);
        if (t == 0) atomicAdd(&ws[n * 4 + 2], hd);
    }
}

__global__ void triplet_finalize(const float* __restrict__ ws,
                                 float* __restrict__ out)
{
    const int i = threadIdx.x;
    if (i < NPART) {
        const float fs = ws[i * 4 + 0];
        const float fc = ws[i * 4 + 1];
        const float hs = ws[i * 4 + 2];
        const float ds = ws[i * 4 + 3];
        out[i]             = (fc == 0.f) ? 0.f : fs / fmaxf(fc, 1.f);
        out[NPART + i]     = hs / (float)M;
        out[2 * NPART + i] = ds / ((float)M * (float)M);
        out[3 * NPART + i] = fc;
    }
}

extern "C" void kernel_launch(void* const* d_in, const int* in_sizes, int n_in,
                              void* d_out, int out_size, void* d_ws, size_t ws_size,
                              hipStream_t stream)
{
    (void)in_sizes; (void)n_in; (void)out_size;
    const float* feat  = (const float*)d_in[0];
    const int*   label = (const int*)d_in[1];
    float*       ws    = (float*)d_ws;

    // ws layout (bytes): [0,992) accum | [4096,131072) x2 | [131072,+16.25MB) hi | then lo
    const size_t HI_OFF = 131072;
    const size_t LO_OFF = HI_OFF + (size_t)NPART * M * D * 2;   // 16384000
    const size_t NEEDED = LO_OFF + (size_t)NPART * M * D * 2;   // 32636928

    hipMemsetAsync(ws, 0, NPART * 4 * sizeof(float), stream);
    if (ws_size >= NEEDED) {
        float* x2_ws = (float*)((char*)d_ws + 4096);
        short* hi_ws = (short*)((char*)d_ws + HI_OFF);
        short* lo_ws = (short*)((char*)d_ws + LO_OFF);
        triplet_prep<<<dim3(NPART * M / 4), 256, 0, stream>>>(feat, x2_ws, hi_ws, lo_ws);
        triplet_main<<<dim3(248), 512, 0, stream>>>(hi_ws, lo_ws, x2_ws, label, ws);
    } else {
        triplet_main_fb<<<dim3(NPART * 8), 256, 0, stream>>>(feat, label, ws);
    }
    triplet_finalize<<<1, 64, 0, stream>>>(ws, (float*)d_out);
}